// Round 10
// baseline (889.460 us; speedup 1.0000x reference)
//
#include <hip/hip_runtime.h>
#include <math.h>

#define B_   64
#define T_   2048
#define HID_ 128
#define G3_  384   // 3*HID
#define IN_  128
#define E_   64

#define TS_  128   // t-tile of gi GEMM block

typedef _Float16 f16x8 __attribute__((ext_vector_type(8)));
typedef float    f32x4 __attribute__((ext_vector_type(4)));

#define L2E  1.4426950408889634f   // log2(e)
#define L2E2 2.8853900817779268f   // 2*log2(e)

#if __has_builtin(__builtin_amdgcn_exp2f)
#define EXP2(x) __builtin_amdgcn_exp2f(x)
#else
#define EXP2(x) __expf((x) * 0.6931471805599453f)
#endif

__device__ __forceinline__ float rcp_(float x) { return __builtin_amdgcn_rcpf(x); }

// pack 8 f32 -> f16x8 via 4x cvt_pkrtz
__device__ __forceinline__ f16x8 pack8_(float4 a, float4 b) {
    uint4 u;
    u.x = __builtin_bit_cast(unsigned, __builtin_amdgcn_cvt_pkrtz(a.x, a.y));
    u.y = __builtin_bit_cast(unsigned, __builtin_amdgcn_cvt_pkrtz(a.z, a.w));
    u.z = __builtin_bit_cast(unsigned, __builtin_amdgcn_cvt_pkrtz(b.x, b.y));
    u.w = __builtin_bit_cast(unsigned, __builtin_amdgcn_cvt_pkrtz(b.z, b.w));
    return __builtin_bit_cast(f16x8, u);
}

// ---------------------------------------------------------------------------
// gi GEMM body (round-8/9-passing version, unchanged math). 8 waves / 512
// threads, two column passes of 12 n-tiles. Wave w owns one 16-row m-tile;
// MFMA layout session-verified (A row = ln, C/D row = kq*4+r, col = ln).
// gi rows chunk-relative; x rows absolute (t0 + tl_base).
// ---------------------------------------------------------------------------
__device__ __forceinline__ void gemm_body(
    int g, int nTiles, int t0,
    const float* __restrict__ x, const float* __restrict__ w_ih,
    const float* __restrict__ b_ih, const float* __restrict__ b_hh,
    float* __restrict__ gi)
{
    const int tid = threadIdx.x;
    const int w   = tid >> 6;      // 0..7
    const int l   = tid & 63;
    const int ln  = l & 15;
    const int kq  = l >> 4;
    const int tt  = g % nTiles;
    const int b   = g / nTiles;
    const int tl_base = tt * TS_ + w * 16;

    const float* xb = x + ((size_t)b * T_ + (size_t)(t0 + tl_base)) * IN_;

    f16x8 afr[4];
    #pragma unroll
    for (int kc = 0; kc < 4; kc++) {
        const float* xr = xb + (size_t)ln * IN_ + kc * 32 + kq * 8;
        float4 p0 = *reinterpret_cast<const float4*>(xr);
        float4 p1 = *reinterpret_cast<const float4*>(xr + 4);
        afr[kc] = pack8_(p0, p1);
    }

    #pragma unroll
    for (int half = 0; half < 2; half++) {
        f32x4 acc[12];
        #pragma unroll
        for (int j = 0; j < 12; j++) acc[j] = (f32x4){0.f, 0.f, 0.f, 0.f};

        #pragma unroll
        for (int kc = 0; kc < 4; kc++) {
            #pragma unroll
            for (int j = 0; j < 12; j++) {
                const int nt = half * 12 + j;
                const float* wr = w_ih + (size_t)(nt * 16 + ln) * IN_ + kc * 32 + kq * 8;
                float4 q0 = *reinterpret_cast<const float4*>(wr);
                float4 q1 = *reinterpret_cast<const float4*>(wr + 4);
                const f16x8 bfr = pack8_(q0, q1);
                acc[j] = __builtin_amdgcn_mfma_f32_16x16x32_f16(afr[kc], bfr, acc[j], 0, 0, 0);
            }
        }

        #pragma unroll
        for (int j = 0; j < 12; j++) {
            const int col = half * 192 + j * 16 + ln;
            const float bias = b_ih[col] + (col < 256 ? b_hh[col] : 0.f);
            #pragma unroll
            for (int r = 0; r < 4; r++) {
                const size_t trow = (size_t)(tl_base + kq * 4 + r);   // chunk-relative
                gi[trow * (B_ * G3_) + (size_t)b * G3_ + col] = acc[j][r] + bias;
            }
        }
    }
}

// ---------------------------------------------------------------------------
// GRU recurrence step. SPLIT ACCUMULATORS (round-5-verified arithmetic:
// per gate, chain A = kc0,kc2 and chain B = kc1,kc3, then one add): halves
// the dependent-MFMA depth feeding each gate (2 chains of 2 vs one chain of
// 4 -- dependent MFMAs can't issue back-to-back, so depth IS latency), and
// gives the SIMD 12 independent chains to fill the matrix pipe. Gate issue
// order: g0, g2, then r's exp2/rcp overlapping g1's MFMAs.
// ---------------------------------------------------------------------------
#define REC_STEP(CUR, LD, TLOAD, PB)                                           \
  {                                                                            \
    const char* hb_ = (const char*)(&h2_sh[PB][0]) + kq * 16;                  \
    f16x8 af_[4];                                                              \
    af_[0] = __builtin_bit_cast(f16x8, *(const uint4*)(hb_));                  \
    af_[1] = __builtin_bit_cast(f16x8, *(const uint4*)(hb_ + 64));             \
    af_[2] = __builtin_bit_cast(f16x8, *(const uint4*)(hb_ + 128));            \
    af_[3] = __builtin_bit_cast(f16x8, *(const uint4*)(hb_ + 192));            \
    const float* gp_ = gib + (size_t)(TLOAD) * S;                              \
    LD[0] = gp_[cg]; LD[1] = gp_[cg + 128]; LD[2] = gp_[cg + 256];             \
    f32x4 zz_ = (f32x4){0.f, 0.f, 0.f, 0.f};                                   \
    f32x4 a0A_ = zz_, a0B_ = zz_, a1A_ = zz_, a1B_ = zz_, a2A_ = zz_, a2B_ = zz_; \
    a0A_ = __builtin_amdgcn_mfma_f32_16x16x32_f16(af_[0], wf[0][0], a0A_, 0, 0, 0); \
    a0B_ = __builtin_amdgcn_mfma_f32_16x16x32_f16(af_[1], wf[0][1], a0B_, 0, 0, 0); \
    a0A_ = __builtin_amdgcn_mfma_f32_16x16x32_f16(af_[2], wf[0][2], a0A_, 0, 0, 0); \
    a0B_ = __builtin_amdgcn_mfma_f32_16x16x32_f16(af_[3], wf[0][3], a0B_, 0, 0, 0); \
    a2A_ = __builtin_amdgcn_mfma_f32_16x16x32_f16(af_[0], wf[2][0], a2A_, 0, 0, 0); \
    a2B_ = __builtin_amdgcn_mfma_f32_16x16x32_f16(af_[1], wf[2][1], a2B_, 0, 0, 0); \
    a2A_ = __builtin_amdgcn_mfma_f32_16x16x32_f16(af_[2], wf[2][2], a2A_, 0, 0, 0); \
    a2B_ = __builtin_amdgcn_mfma_f32_16x16x32_f16(af_[3], wf[2][3], a2B_, 0, 0, 0); \
    const float yr_ = fmaf(CUR[0], L2E, a0A_[0] + a0B_[0]);                    \
    const float r_  = rcp_(1.f + EXP2(-yr_));                                  \
    a1A_ = __builtin_amdgcn_mfma_f32_16x16x32_f16(af_[0], wf[1][0], a1A_, 0, 0, 0); \
    a1B_ = __builtin_amdgcn_mfma_f32_16x16x32_f16(af_[1], wf[1][1], a1B_, 0, 0, 0); \
    a1A_ = __builtin_amdgcn_mfma_f32_16x16x32_f16(af_[2], wf[1][2], a1A_, 0, 0, 0); \
    a1B_ = __builtin_amdgcn_mfma_f32_16x16x32_f16(af_[3], wf[1][3], a1B_, 0, 0, 0); \
    const float q_  = CUR[2] * L2E2;                                           \
    const float yn_ = fmaf(r_, a2A_[0] + a2B_[0] + bh, q_);                    \
    const float u_  = rcp_(1.f + EXP2(yn_));                                   \
    const float n_  = fmaf(-2.f, u_, 1.f);                                     \
    const float yz_ = fmaf(CUR[1], L2E, a1A_[0] + a1B_[0]);                    \
    const float z_  = rcp_(1.f + EXP2(-yz_));                                  \
    hj = n_ + z_ * (hj - n_);                                                  \
    hs += hj;                                                                  \
    if (kq == 0) h2_sh[(PB) ^ 1][cg] = (_Float16)hj;                           \
    __syncthreads();                                                           \
  }

__device__ __forceinline__ void rec_body(
    int b,
    const float* __restrict__ gi, const float* __restrict__ w_hh,
    const float* __restrict__ b_hh,
    const float* __restrict__ w_proj, const float* __restrict__ b_proj,
    float* __restrict__ out, float* __restrict__ state,
    int t0, int t1)
{
    const int tid  = threadIdx.x;
    const int w    = tid >> 6;     // wave 0..7
    const int lane = tid & 63;
    const int ln   = lane & 15;
    const int kq   = lane >> 4;
    const int wh   = w & 3;
    const int f    = w >> 2;
    const int cg   = 16 * wh + ln + 64 * f;
    const int nT   = t1 - t0;      // multiple of 4

    __shared__ _Float16 h2_sh[2][HID_];
    __shared__ float pooled[HID_];

    // B-frags pre-scaled: r,z by log2(e); n by 2*log2(e) (exp2-direct gates)
    f16x8 wf[3][4];
    #pragma unroll
    for (int g = 0; g < 3; g++) {
        const float s = (g == 2) ? L2E2 : L2E;
        const float* wr = w_hh + (size_t)(128 * g + cg) * HID_;
        #pragma unroll
        for (int kc = 0; kc < 4; kc++) {
            const float* p = wr + kc * 32 + kq * 8;
            float4 q0 = *reinterpret_cast<const float4*>(p);
            float4 q1 = *reinterpret_cast<const float4*>(p + 4);
            q0.x *= s; q0.y *= s; q0.z *= s; q0.w *= s;
            q1.x *= s; q1.y *= s; q1.z *= s; q1.w *= s;
            wf[g][kc] = pack8_(q0, q1);
        }
    }
    const float bh = L2E2 * b_hh[256 + cg];

    float hj, hs;
    if (t0 == 0) { hj = hs = 0.f; }
    else {
        hj = state[b * HID_ + cg];
        hs = state[B_ * HID_ + b * HID_ + cg];
    }
    if (kq == 0) h2_sh[0][cg] = (_Float16)hj;
    __syncthreads();

    const float* gib = gi + (size_t)b * G3_;
    const size_t S = (size_t)B_ * G3_;

    float g0[3], g1[3], g2[3], g3[3];
    {
        const float* p0 = gib;
        const float* p1 = gib + S;
        g0[0] = p0[cg]; g0[1] = p0[cg + 128]; g0[2] = p0[cg + 256];
        g1[0] = p1[cg]; g1[1] = p1[cg + 128]; g1[2] = p1[cg + 256];
    }

    int pb = 0;
    const int nTm1 = nT - 1;
    for (int t = 0; t < nT; t += 4) {
        int t2 = t + 2 < nTm1 ? t + 2 : nTm1;
        int t3 = t + 3 < nTm1 ? t + 3 : nTm1;
        int t4 = t + 4 < nTm1 ? t + 4 : nTm1;
        int t5 = t + 5 < nTm1 ? t + 5 : nTm1;
        REC_STEP(g0, g2, t2, pb); pb ^= 1;
        REC_STEP(g1, g3, t3, pb); pb ^= 1;
        REC_STEP(g2, g0, t4, pb); pb ^= 1;
        REC_STEP(g3, g1, t5, pb); pb ^= 1;
    }

    if (t1 < T_) {
        if (kq == 0) {
            state[b * HID_ + cg]             = hj;
            state[B_ * HID_ + b * HID_ + cg] = hs;
        }
    } else {
        if (kq == 0) pooled[cg] = hs * (1.f / (float)T_);
        __syncthreads();
        if (tid < E_) {
            const float4* wpj = reinterpret_cast<const float4*>(w_proj + (size_t)tid * HID_);
            const float4* pp  = reinterpret_cast<const float4*>(pooled);
            float a0 = 0.f, a1 = 0.f, a2 = 0.f, a3 = 0.f;
            #pragma unroll
            for (int k = 0; k < 32; k++) {
                float4 wv = wpj[k]; float4 pv = pp[k];
                a0 = fmaf(wv.x, pv.x, a0);
                a1 = fmaf(wv.y, pv.y, a1);
                a2 = fmaf(wv.z, pv.z, a2);
                a3 = fmaf(wv.w, pv.w, a3);
            }
            out[b * E_ + tid] = (a0 + a1) + (a2 + a3) + b_proj[tid];
        }
    }
}

// ---------------------------------------------------------------------------
// Fused pipeline dispatch: blocks [0, nRec) run rec(chunk i-1); blocks
// [nRec, gridDim) are gemm producers GRID-STRIDING over nJobs jobs of
// chunk i. Producer count is capped (<=160) so grid <= 224 <= 256 CUs:
// zero queued blocks, no scheduler churn, bounded L3 pressure (the r9
// 576-640-block co-run bursts were the +68us model error). rec reads the
// gi buffer written by the PREVIOUS dispatch (stream order).
// ---------------------------------------------------------------------------
__global__ __launch_bounds__(512, 1)
void fused(const float* __restrict__ x, const float* __restrict__ w_ih,
           const float* __restrict__ b_ih, const float* __restrict__ w_hh,
           const float* __restrict__ b_hh,
           const float* __restrict__ w_proj, const float* __restrict__ b_proj,
           const float* __restrict__ gi_rec, float* __restrict__ gi_out,
           float* __restrict__ out, float* __restrict__ state,
           int trec0, int trec1, int tg0, int nRec, int nTiles, int nJobs)
{
    const int bid = (int)blockIdx.x;
    if (bid < nRec) {
        rec_body(bid, gi_rec, w_hh, b_hh, w_proj, b_proj, out, state, trec0, trec1);
    } else {
        const int np = (int)gridDim.x - nRec;
        for (int j = bid - nRec; j < nJobs; j += np)
            gemm_body(j, nTiles, tg0, x, w_ih, b_ih, b_hh, gi_out);
    }
}

extern "C" void kernel_launch(void* const* d_in, const int* in_sizes, int n_in,
                              void* d_out, int out_size, void* d_ws, size_t ws_size,
                              hipStream_t stream)
{
    const float* x      = (const float*)d_in[0];
    const float* w_ih   = (const float*)d_in[1];
    const float* w_hh   = (const float*)d_in[2];
    const float* b_ih   = (const float*)d_in[3];
    const float* b_hh   = (const float*)d_in[4];
    const float* w_proj = (const float*)d_in[5];
    const float* b_proj = (const float*)d_in[6];
    float* out = (float*)d_out;

    const size_t state_bytes = (size_t)2 * B_ * HID_ * sizeof(float);
    const size_t per_t = (size_t)B_ * G3_ * sizeof(float);

    // Schedule {256, 512, 1280}: gemm(c[i]) covered by rec(c[i-1]) with
    // >=1.7x margin at 160-producer throughput (~7 jobs/us); big tail runs
    // at the faster no-contention step rate.
    const int NCK = 3;
    const int ck[NCK] = {256, 512, 1280};
    const size_t buf0_rows = 1280, buf1_rows = 512;   // c0,c2 -> buf0; c1 -> buf1
    const size_t need = (buf0_rows + buf1_rows) * per_t + state_bytes;
    const int GMAX = 160;   // producer block cap: 64 rec + 160 gemm = 224 <= 256 CUs

    if (ws_size >= need) {
        float* buf[2] = { (float*)d_ws,
                          (float*)((char*)d_ws + buf0_rows * per_t) };
        float* state  = (float*)((char*)d_ws + (buf0_rows + buf1_rows) * per_t);
        int st[NCK + 1];
        st[0] = 0;
        for (int i = 0; i < NCK; i++) st[i + 1] = st[i] + ck[i];
        for (int i = 0; i <= NCK; i++) {
            const int rb    = (i > 0)   ? B_ : 0;
            const int jobs  = (i < NCK) ? (ck[i] / TS_) * B_ : 0;
            const int gb    = jobs > GMAX ? GMAX : jobs;
            const int trec0 = (i > 0) ? st[i - 1] : 0;
            const int trec1 = (i > 0) ? st[i]     : 0;
            const int tg0   = (i < NCK) ? st[i] : 0;
            const int nT    = (i < NCK) ? ck[i] / TS_ : 1;
            fused<<<dim3(rb + gb), dim3(512), 0, stream>>>(
                x, w_ih, b_ih, w_hh, b_hh, w_proj, b_proj,
                buf[(i + 1) & 1] /* = buf[(i-1)&1] */, buf[i & 1],
                out, state, trec0, trec1, tg0, rb, nT, jobs);
        }
    } else {
        // Serial fallback: single buffer, gemm dispatch then rec dispatch.
        size_t avail = ws_size > state_bytes ? ws_size - state_bytes : 0;
        int cT = (int)(avail / per_t);
        if (cT > T_) cT = T_;
        cT &= ~(TS_ - 1);
        if (cT < TS_) cT = TS_;
        float* buf0  = (float*)d_ws;
        float* state = (float*)((char*)d_ws + (size_t)cT * per_t);
        for (int t0 = 0; t0 < T_; t0 += cT) {
            int t1 = t0 + cT; if (t1 > T_) t1 = T_;
            int nt = t1 - t0;
            const int jobs = (nt / TS_) * B_;
            fused<<<dim3(jobs), dim3(512), 0, stream>>>(
                x, w_ih, b_ih, w_hh, b_hh, w_proj, b_proj,
                buf0, buf0, out, state, 0, 0, t0, 0, nt / TS_, jobs);
            fused<<<dim3(B_), dim3(512), 0, stream>>>(
                x, w_ih, b_ih, w_hh, b_hh, w_proj, b_proj,
                buf0, buf0, out, state, t0, t1, 0, B_, nt / TS_, 0);
        }
    }
}

// Round 11
// 877.097 us; speedup vs baseline: 1.0141x; 1.0141x over previous
//
#include <hip/hip_runtime.h>
#include <math.h>

#define B_   64
#define T_   2048
#define HID_ 128
#define G3_  384   // 3*HID
#define IN_  128
#define E_   64

#define TS_  128   // t-tile of gi GEMM block

typedef _Float16 f16x8 __attribute__((ext_vector_type(8)));
typedef float    f32x4 __attribute__((ext_vector_type(4)));

#define L2E  1.4426950408889634f   // log2(e)
#define L2E2 2.8853900817779268f   // 2*log2(e)

#if __has_builtin(__builtin_amdgcn_exp2f)
#define EXP2(x) __builtin_amdgcn_exp2f(x)
#else
#define EXP2(x) __expf((x) * 0.6931471805599453f)
#endif

__device__ __forceinline__ float rcp_(float x) { return __builtin_amdgcn_rcpf(x); }

// pack 8 f32 -> f16x8 via 4x cvt_pkrtz
__device__ __forceinline__ f16x8 pack8_(float4 a, float4 b) {
    uint4 u;
    u.x = __builtin_bit_cast(unsigned, __builtin_amdgcn_cvt_pkrtz(a.x, a.y));
    u.y = __builtin_bit_cast(unsigned, __builtin_amdgcn_cvt_pkrtz(a.z, a.w));
    u.z = __builtin_bit_cast(unsigned, __builtin_amdgcn_cvt_pkrtz(b.x, b.y));
    u.w = __builtin_bit_cast(unsigned, __builtin_amdgcn_cvt_pkrtz(b.z, b.w));
    return __builtin_bit_cast(f16x8, u);
}

// ---------------------------------------------------------------------------
// gi GEMM body (round-8/9-passing version, unchanged). 8 waves / 512
// threads, two column passes of 12 n-tiles. Wave w owns one 16-row m-tile;
// MFMA layout session-verified (A row = ln, C/D row = kq*4+r, col = ln).
// gi rows chunk-relative; x rows absolute (t0 + tl_base).
// ---------------------------------------------------------------------------
__device__ __forceinline__ void gemm_body(
    int g, int nTiles, int t0,
    const float* __restrict__ x, const float* __restrict__ w_ih,
    const float* __restrict__ b_ih, const float* __restrict__ b_hh,
    float* __restrict__ gi)
{
    const int tid = threadIdx.x;
    const int w   = tid >> 6;      // 0..7
    const int l   = tid & 63;
    const int ln  = l & 15;
    const int kq  = l >> 4;
    const int tt  = g % nTiles;
    const int b   = g / nTiles;
    const int tl_base = tt * TS_ + w * 16;

    const float* xb = x + ((size_t)b * T_ + (size_t)(t0 + tl_base)) * IN_;

    f16x8 afr[4];
    #pragma unroll
    for (int kc = 0; kc < 4; kc++) {
        const float* xr = xb + (size_t)ln * IN_ + kc * 32 + kq * 8;
        float4 p0 = *reinterpret_cast<const float4*>(xr);
        float4 p1 = *reinterpret_cast<const float4*>(xr + 4);
        afr[kc] = pack8_(p0, p1);
    }

    #pragma unroll
    for (int half = 0; half < 2; half++) {
        f32x4 acc[12];
        #pragma unroll
        for (int j = 0; j < 12; j++) acc[j] = (f32x4){0.f, 0.f, 0.f, 0.f};

        #pragma unroll
        for (int kc = 0; kc < 4; kc++) {
            #pragma unroll
            for (int j = 0; j < 12; j++) {
                const int nt = half * 12 + j;
                const float* wr = w_ih + (size_t)(nt * 16 + ln) * IN_ + kc * 32 + kq * 8;
                float4 q0 = *reinterpret_cast<const float4*>(wr);
                float4 q1 = *reinterpret_cast<const float4*>(wr + 4);
                const f16x8 bfr = pack8_(q0, q1);
                acc[j] = __builtin_amdgcn_mfma_f32_16x16x32_f16(afr[kc], bfr, acc[j], 0, 0, 0);
            }
        }

        #pragma unroll
        for (int j = 0; j < 12; j++) {
            const int col = half * 192 + j * 16 + ln;
            const float bias = b_ih[col] + (col < 256 ? b_hh[col] : 0.f);
            #pragma unroll
            for (int r = 0; r < 4; r++) {
                const size_t trow = (size_t)(tl_base + kq * 4 + r);   // chunk-relative
                gi[trow * (B_ * G3_) + (size_t)b * G3_ + col] = acc[j][r] + bias;
            }
        }
    }
}

// ---------------------------------------------------------------------------
// GRU recurrence step -- round-9-verified version (VGPR 64, tail-measured
// 781 cyc/step). r10's split accumulators were measured NEUTRAL on step
// time (+64 VGPR) and are reverted. Issue order: g0's MFMAs, g2's, r's
// exp2/rcp chain overlapping g1's MFMAs, then n, then z.
// ---------------------------------------------------------------------------
#define REC_STEP(CUR, LD, TLOAD, PB)                                           \
  {                                                                            \
    const char* hb_ = (const char*)(&h2_sh[PB][0]) + kq * 16;                  \
    f16x8 af_[4];                                                              \
    af_[0] = __builtin_bit_cast(f16x8, *(const uint4*)(hb_));                  \
    af_[1] = __builtin_bit_cast(f16x8, *(const uint4*)(hb_ + 64));             \
    af_[2] = __builtin_bit_cast(f16x8, *(const uint4*)(hb_ + 128));            \
    af_[3] = __builtin_bit_cast(f16x8, *(const uint4*)(hb_ + 192));            \
    const float* gp_ = gib + (size_t)(TLOAD) * S;                              \
    LD[0] = gp_[cg]; LD[1] = gp_[cg + 128]; LD[2] = gp_[cg + 256];             \
    f32x4 a0_ = (f32x4){0.f, 0.f, 0.f, 0.f};                                   \
    f32x4 a1_ = (f32x4){0.f, 0.f, 0.f, 0.f};                                   \
    f32x4 a2_ = (f32x4){0.f, 0.f, 0.f, 0.f};                                   \
    a0_ = __builtin_amdgcn_mfma_f32_16x16x32_f16(af_[0], wf[0][0], a0_, 0, 0, 0); \
    a0_ = __builtin_amdgcn_mfma_f32_16x16x32_f16(af_[1], wf[0][1], a0_, 0, 0, 0); \
    a0_ = __builtin_amdgcn_mfma_f32_16x16x32_f16(af_[2], wf[0][2], a0_, 0, 0, 0); \
    a0_ = __builtin_amdgcn_mfma_f32_16x16x32_f16(af_[3], wf[0][3], a0_, 0, 0, 0); \
    a2_ = __builtin_amdgcn_mfma_f32_16x16x32_f16(af_[0], wf[2][0], a2_, 0, 0, 0); \
    a2_ = __builtin_amdgcn_mfma_f32_16x16x32_f16(af_[1], wf[2][1], a2_, 0, 0, 0); \
    a2_ = __builtin_amdgcn_mfma_f32_16x16x32_f16(af_[2], wf[2][2], a2_, 0, 0, 0); \
    a2_ = __builtin_amdgcn_mfma_f32_16x16x32_f16(af_[3], wf[2][3], a2_, 0, 0, 0); \
    const float yr_ = fmaf(CUR[0], L2E, a0_[0]);                               \
    const float r_  = rcp_(1.f + EXP2(-yr_));                                  \
    a1_ = __builtin_amdgcn_mfma_f32_16x16x32_f16(af_[0], wf[1][0], a1_, 0, 0, 0); \
    a1_ = __builtin_amdgcn_mfma_f32_16x16x32_f16(af_[1], wf[1][1], a1_, 0, 0, 0); \
    a1_ = __builtin_amdgcn_mfma_f32_16x16x32_f16(af_[2], wf[1][2], a1_, 0, 0, 0); \
    a1_ = __builtin_amdgcn_mfma_f32_16x16x32_f16(af_[3], wf[1][3], a1_, 0, 0, 0); \
    const float q_  = CUR[2] * L2E2;                                           \
    const float yn_ = fmaf(r_, a2_[0] + bh, q_);                               \
    const float u_  = rcp_(1.f + EXP2(yn_));                                   \
    const float n_  = fmaf(-2.f, u_, 1.f);                                     \
    const float yz_ = fmaf(CUR[1], L2E, a1_[0]);                               \
    const float z_  = rcp_(1.f + EXP2(-yz_));                                  \
    hj = n_ + z_ * (hj - n_);                                                  \
    hs += hj;                                                                  \
    if (kq == 0) h2_sh[(PB) ^ 1][cg] = (_Float16)hj;                           \
    __syncthreads();                                                           \
  }

__device__ __forceinline__ void rec_body(
    int b,
    const float* __restrict__ gi, const float* __restrict__ w_hh,
    const float* __restrict__ b_hh,
    const float* __restrict__ w_proj, const float* __restrict__ b_proj,
    float* __restrict__ out, float* __restrict__ state,
    int t0, int t1)
{
    const int tid  = threadIdx.x;
    const int w    = tid >> 6;     // wave 0..7
    const int lane = tid & 63;
    const int ln   = lane & 15;
    const int kq   = lane >> 4;
    const int wh   = w & 3;
    const int f    = w >> 2;
    const int cg   = 16 * wh + ln + 64 * f;
    const int nT   = t1 - t0;      // multiple of 4

    __shared__ _Float16 h2_sh[2][HID_];
    __shared__ float pooled[HID_];

    // B-frags pre-scaled: r,z by log2(e); n by 2*log2(e) (exp2-direct gates)
    f16x8 wf[3][4];
    #pragma unroll
    for (int g = 0; g < 3; g++) {
        const float s = (g == 2) ? L2E2 : L2E;
        const float* wr = w_hh + (size_t)(128 * g + cg) * HID_;
        #pragma unroll
        for (int kc = 0; kc < 4; kc++) {
            const float* p = wr + kc * 32 + kq * 8;
            float4 q0 = *reinterpret_cast<const float4*>(p);
            float4 q1 = *reinterpret_cast<const float4*>(p + 4);
            q0.x *= s; q0.y *= s; q0.z *= s; q0.w *= s;
            q1.x *= s; q1.y *= s; q1.z *= s; q1.w *= s;
            wf[g][kc] = pack8_(q0, q1);
        }
    }
    const float bh = L2E2 * b_hh[256 + cg];

    float hj, hs;
    if (t0 == 0) { hj = hs = 0.f; }
    else {
        hj = state[b * HID_ + cg];
        hs = state[B_ * HID_ + b * HID_ + cg];
    }
    if (kq == 0) h2_sh[0][cg] = (_Float16)hj;
    __syncthreads();

    const float* gib = gi + (size_t)b * G3_;
    const size_t S = (size_t)B_ * G3_;

    float g0[3], g1[3], g2[3], g3[3];
    {
        const float* p0 = gib;
        const float* p1 = gib + S;
        g0[0] = p0[cg]; g0[1] = p0[cg + 128]; g0[2] = p0[cg + 256];
        g1[0] = p1[cg]; g1[1] = p1[cg + 128]; g1[2] = p1[cg + 256];
    }

    int pb = 0;
    const int nTm1 = nT - 1;
    for (int t = 0; t < nT; t += 4) {
        int t2 = t + 2 < nTm1 ? t + 2 : nTm1;
        int t3 = t + 3 < nTm1 ? t + 3 : nTm1;
        int t4 = t + 4 < nTm1 ? t + 4 : nTm1;
        int t5 = t + 5 < nTm1 ? t + 5 : nTm1;
        REC_STEP(g0, g2, t2, pb); pb ^= 1;
        REC_STEP(g1, g3, t3, pb); pb ^= 1;
        REC_STEP(g2, g0, t4, pb); pb ^= 1;
        REC_STEP(g3, g1, t5, pb); pb ^= 1;
    }

    if (t1 < T_) {
        if (kq == 0) {
            state[b * HID_ + cg]             = hj;
            state[B_ * HID_ + b * HID_ + cg] = hs;
        }
    } else {
        if (kq == 0) pooled[cg] = hs * (1.f / (float)T_);
        __syncthreads();
        if (tid < E_) {
            const float4* wpj = reinterpret_cast<const float4*>(w_proj + (size_t)tid * HID_);
            const float4* pp  = reinterpret_cast<const float4*>(pooled);
            float a0 = 0.f, a1 = 0.f, a2 = 0.f, a3 = 0.f;
            #pragma unroll
            for (int k = 0; k < 32; k++) {
                float4 wv = wpj[k]; float4 pv = pp[k];
                a0 = fmaf(wv.x, pv.x, a0);
                a1 = fmaf(wv.y, pv.y, a1);
                a2 = fmaf(wv.z, pv.z, a2);
                a3 = fmaf(wv.w, pv.w, a3);
            }
            out[b * E_ + tid] = (a0 + a1) + (a2 + a3) + b_proj[tid];
        }
    }
}

// ---------------------------------------------------------------------------
// Fused pipeline dispatch: blocks [0, nRec) run rec(chunk i-1), blocks
// [nRec, ...) run one gi_gemm job each for chunk i. rec reads the gi buffer
// written by the PREVIOUS dispatch (stream order = happens-before).
// KEY r11 change: launched with an 80 KB dynamic-LDS pad -> exactly 1
// block/CU. r9/r10 counters showed 64-VGPR/1KB-LDS blocks co-reside up to
// 4/CU, so gemm blocks landed ON the rec CUs and stole their matrix pipe
// (co-run rec steps ran ~1078 cyc vs 781 isolated -- the entire co-run
// tax). With the pad, rec's 64 CUs are exclusive; gemm uses the other 192.
// ---------------------------------------------------------------------------
__global__ __launch_bounds__(512, 1)
void fused(const float* __restrict__ x, const float* __restrict__ w_ih,
           const float* __restrict__ b_ih, const float* __restrict__ w_hh,
           const float* __restrict__ b_hh,
           const float* __restrict__ w_proj, const float* __restrict__ b_proj,
           const float* __restrict__ gi_rec, float* __restrict__ gi_out,
           float* __restrict__ out, float* __restrict__ state,
           int trec0, int trec1, int tg0, int nRec, int nTiles)
{
    extern __shared__ char lds_pad_[];   // sized via launch config (pad only)
    (void)lds_pad_;
    const int bid = (int)blockIdx.x;
    if (bid < nRec) {
        rec_body(bid, gi_rec, w_hh, b_hh, w_proj, b_proj, out, state, trec0, trec1);
    } else {
        gemm_body(bid - nRec, nTiles, tg0, x, w_ih, b_ih, b_hh, gi_out);
    }
}

extern "C" void kernel_launch(void* const* d_in, const int* in_sizes, int n_in,
                              void* d_out, int out_size, void* d_ws, size_t ws_size,
                              hipStream_t stream)
{
    const float* x      = (const float*)d_in[0];
    const float* w_ih   = (const float*)d_in[1];
    const float* w_hh   = (const float*)d_in[2];
    const float* b_ih   = (const float*)d_in[3];
    const float* b_hh   = (const float*)d_in[4];
    const float* w_proj = (const float*)d_in[5];
    const float* b_proj = (const float*)d_in[6];
    float* out = (float*)d_out;

    const size_t state_bytes = (size_t)2 * B_ * HID_ * sizeof(float);
    const size_t per_t = (size_t)B_ * G3_ * sizeof(float);
    const unsigned LDS_PAD = 80 * 1024;   // force 1 block/CU

    // Schedule {128, 384, 1536}: minimal exposed prologue (gemm128 ~25us),
    // only 512 co-run steps, then a 1536-step contention-free tail.
    // Feasibility: gemm384 (~22us on 192 CUs) < rec128 (~42us);
    // gemm1536 (768 jobs, 4 rounds ~88us) < rec384 (~125us).
    const int NCK = 3;
    const int ck[NCK] = {128, 384, 1536};
    const size_t buf0_rows = 1536, buf1_rows = 384;   // c0,c2 -> buf0; c1 -> buf1
    const size_t need = (buf0_rows + buf1_rows) * per_t + state_bytes;

    if (ws_size >= need) {
        float* buf[2] = { (float*)d_ws,
                          (float*)((char*)d_ws + buf0_rows * per_t) };
        float* state  = (float*)((char*)d_ws + (buf0_rows + buf1_rows) * per_t);
        int st[NCK + 1];
        st[0] = 0;
        for (int i = 0; i < NCK; i++) st[i + 1] = st[i] + ck[i];
        for (int i = 0; i <= NCK; i++) {
            const int rb    = (i > 0)   ? B_ : 0;
            const int gb    = (i < NCK) ? (ck[i] / TS_) * B_ : 0;
            const int trec0 = (i > 0) ? st[i - 1] : 0;
            const int trec1 = (i > 0) ? st[i]     : 0;
            const int tg0   = (i < NCK) ? st[i] : 0;
            const int nT    = (i < NCK) ? ck[i] / TS_ : 1;
            fused<<<dim3(rb + gb), dim3(512), LDS_PAD, stream>>>(
                x, w_ih, b_ih, w_hh, b_hh, w_proj, b_proj,
                buf[(i + 1) & 1] /* = buf[(i-1)&1] */, buf[i & 1],
                out, state, trec0, trec1, tg0, rb, nT);
        }
    } else {
        // Serial fallback: single buffer, gemm dispatch then rec dispatch
        // (no LDS pad -- dense gemm grids want multi-block residency).
        size_t avail = ws_size > state_bytes ? ws_size - state_bytes : 0;
        int cT = (int)(avail / per_t);
        if (cT > T_) cT = T_;
        cT &= ~(TS_ - 1);
        if (cT < TS_) cT = TS_;
        float* buf0  = (float*)d_ws;
        float* state = (float*)((char*)d_ws + (size_t)cT * per_t);
        for (int t0 = 0; t0 < T_; t0 += cT) {
            int t1 = t0 + cT; if (t1 > T_) t1 = T_;
            int nt = t1 - t0;
            fused<<<dim3((nt / TS_) * B_), dim3(512), 0, stream>>>(
                x, w_ih, b_ih, w_hh, b_hh, w_proj, b_proj,
                buf0, buf0, out, state, 0, 0, t0, 0, nt / TS_);
            fused<<<dim3(B_), dim3(512), 0, stream>>>(
                x, w_ih, b_ih, w_hh, b_hh, w_proj, b_proj,
                buf0, buf0, out, state, t0, t1, 0, B_, nt / TS_);
        }
    }
}

// Round 12
// 873.559 us; speedup vs baseline: 1.0182x; 1.0041x over previous
//
#include <hip/hip_runtime.h>
#include <math.h>

#define B_   64
#define T_   2048
#define HID_ 128
#define G3_  384   // 3*HID
#define IN_  128
#define E_   64

#define TS_  128   // t-tile of gi GEMM block

typedef _Float16 f16x8 __attribute__((ext_vector_type(8)));
typedef float    f32x4 __attribute__((ext_vector_type(4)));

#define L2E  1.4426950408889634f   // log2(e)
#define L2E2 2.8853900817779268f   // 2*log2(e)

#if __has_builtin(__builtin_amdgcn_exp2f)
#define EXP2(x) __builtin_amdgcn_exp2f(x)
#else
#define EXP2(x) __expf((x) * 0.6931471805599453f)
#endif

__device__ __forceinline__ float rcp_(float x) { return __builtin_amdgcn_rcpf(x); }

// pack 8 f32 -> f16x8 via 4x cvt_pkrtz
__device__ __forceinline__ f16x8 pack8_(float4 a, float4 b) {
    uint4 u;
    u.x = __builtin_bit_cast(unsigned, __builtin_amdgcn_cvt_pkrtz(a.x, a.y));
    u.y = __builtin_bit_cast(unsigned, __builtin_amdgcn_cvt_pkrtz(a.z, a.w));
    u.z = __builtin_bit_cast(unsigned, __builtin_amdgcn_cvt_pkrtz(b.x, b.y));
    u.w = __builtin_bit_cast(unsigned, __builtin_amdgcn_cvt_pkrtz(b.z, b.w));
    return __builtin_bit_cast(f16x8, u);
}

// ---------------------------------------------------------------------------
// gi GEMM body (round-8/9/11-passing version, unchanged). 8 waves / 512
// threads, two column passes of 12 n-tiles. Wave w owns one 16-row m-tile;
// MFMA layout session-verified (A row = ln, C/D row = kq*4+r, col = ln).
// gi rows chunk-relative; x rows absolute (t0 + tl_base).
// ---------------------------------------------------------------------------
__device__ __forceinline__ void gemm_body(
    int g, int nTiles, int t0,
    const float* __restrict__ x, const float* __restrict__ w_ih,
    const float* __restrict__ b_ih, const float* __restrict__ b_hh,
    float* __restrict__ gi)
{
    const int tid = threadIdx.x;
    const int w   = tid >> 6;      // 0..7
    const int l   = tid & 63;
    const int ln  = l & 15;
    const int kq  = l >> 4;
    const int tt  = g % nTiles;
    const int b   = g / nTiles;
    const int tl_base = tt * TS_ + w * 16;

    const float* xb = x + ((size_t)b * T_ + (size_t)(t0 + tl_base)) * IN_;

    f16x8 afr[4];
    #pragma unroll
    for (int kc = 0; kc < 4; kc++) {
        const float* xr = xb + (size_t)ln * IN_ + kc * 32 + kq * 8;
        float4 p0 = *reinterpret_cast<const float4*>(xr);
        float4 p1 = *reinterpret_cast<const float4*>(xr + 4);
        afr[kc] = pack8_(p0, p1);
    }

    #pragma unroll
    for (int half = 0; half < 2; half++) {
        f32x4 acc[12];
        #pragma unroll
        for (int j = 0; j < 12; j++) acc[j] = (f32x4){0.f, 0.f, 0.f, 0.f};

        #pragma unroll
        for (int kc = 0; kc < 4; kc++) {
            #pragma unroll
            for (int j = 0; j < 12; j++) {
                const int nt = half * 12 + j;
                const float* wr = w_ih + (size_t)(nt * 16 + ln) * IN_ + kc * 32 + kq * 8;
                float4 q0 = *reinterpret_cast<const float4*>(wr);
                float4 q1 = *reinterpret_cast<const float4*>(wr + 4);
                const f16x8 bfr = pack8_(q0, q1);
                acc[j] = __builtin_amdgcn_mfma_f32_16x16x32_f16(afr[kc], bfr, acc[j], 0, 0, 0);
            }
        }

        #pragma unroll
        for (int j = 0; j < 12; j++) {
            const int col = half * 192 + j * 16 + ln;
            const float bias = b_ih[col] + (col < 256 ? b_hh[col] : 0.f);
            #pragma unroll
            for (int r = 0; r < 4; r++) {
                const size_t trow = (size_t)(tl_base + kq * 4 + r);   // chunk-relative
                gi[trow * (B_ * G3_) + (size_t)b * G3_ + col] = acc[j][r] + bias;
            }
        }
    }
}

// ---------------------------------------------------------------------------
// GRU recurrence step -- round-9-verified version (VGPR 64, tail-measured
// 776-781 cyc/step across r9/r10/r11). Issue order: g0's MFMAs, g2's, r's
// exp2/rcp chain overlapping g1's MFMAs, then n, then z.
// ---------------------------------------------------------------------------
#define REC_STEP(CUR, LD, TLOAD, PB)                                           \
  {                                                                            \
    const char* hb_ = (const char*)(&h2_sh[PB][0]) + kq * 16;                  \
    f16x8 af_[4];                                                              \
    af_[0] = __builtin_bit_cast(f16x8, *(const uint4*)(hb_));                  \
    af_[1] = __builtin_bit_cast(f16x8, *(const uint4*)(hb_ + 64));             \
    af_[2] = __builtin_bit_cast(f16x8, *(const uint4*)(hb_ + 128));            \
    af_[3] = __builtin_bit_cast(f16x8, *(const uint4*)(hb_ + 192));            \
    const float* gp_ = gib + (size_t)(TLOAD) * S;                              \
    LD[0] = gp_[cg]; LD[1] = gp_[cg + 128]; LD[2] = gp_[cg + 256];             \
    f32x4 a0_ = (f32x4){0.f, 0.f, 0.f, 0.f};                                   \
    f32x4 a1_ = (f32x4){0.f, 0.f, 0.f, 0.f};                                   \
    f32x4 a2_ = (f32x4){0.f, 0.f, 0.f, 0.f};                                   \
    a0_ = __builtin_amdgcn_mfma_f32_16x16x32_f16(af_[0], wf[0][0], a0_, 0, 0, 0); \
    a0_ = __builtin_amdgcn_mfma_f32_16x16x32_f16(af_[1], wf[0][1], a0_, 0, 0, 0); \
    a0_ = __builtin_amdgcn_mfma_f32_16x16x32_f16(af_[2], wf[0][2], a0_, 0, 0, 0); \
    a0_ = __builtin_amdgcn_mfma_f32_16x16x32_f16(af_[3], wf[0][3], a0_, 0, 0, 0); \
    a2_ = __builtin_amdgcn_mfma_f32_16x16x32_f16(af_[0], wf[2][0], a2_, 0, 0, 0); \
    a2_ = __builtin_amdgcn_mfma_f32_16x16x32_f16(af_[1], wf[2][1], a2_, 0, 0, 0); \
    a2_ = __builtin_amdgcn_mfma_f32_16x16x32_f16(af_[2], wf[2][2], a2_, 0, 0, 0); \
    a2_ = __builtin_amdgcn_mfma_f32_16x16x32_f16(af_[3], wf[2][3], a2_, 0, 0, 0); \
    const float yr_ = fmaf(CUR[0], L2E, a0_[0]);                               \
    const float r_  = rcp_(1.f + EXP2(-yr_));                                  \
    a1_ = __builtin_amdgcn_mfma_f32_16x16x32_f16(af_[0], wf[1][0], a1_, 0, 0, 0); \
    a1_ = __builtin_amdgcn_mfma_f32_16x16x32_f16(af_[1], wf[1][1], a1_, 0, 0, 0); \
    a1_ = __builtin_amdgcn_mfma_f32_16x16x32_f16(af_[2], wf[1][2], a1_, 0, 0, 0); \
    a1_ = __builtin_amdgcn_mfma_f32_16x16x32_f16(af_[3], wf[1][3], a1_, 0, 0, 0); \
    const float q_  = CUR[2] * L2E2;                                           \
    const float yn_ = fmaf(r_, a2_[0] + bh, q_);                               \
    const float u_  = rcp_(1.f + EXP2(yn_));                                   \
    const float n_  = fmaf(-2.f, u_, 1.f);                                     \
    const float yz_ = fmaf(CUR[1], L2E, a1_[0]);                               \
    const float z_  = rcp_(1.f + EXP2(-yz_));                                  \
    hj = n_ + z_ * (hj - n_);                                                  \
    hs += hj;                                                                  \
    if (kq == 0) h2_sh[(PB) ^ 1][cg] = (_Float16)hj;                           \
    __syncthreads();                                                           \
  }

__device__ __forceinline__ void rec_body(
    int b,
    const float* __restrict__ gi, const float* __restrict__ w_hh,
    const float* __restrict__ b_hh,
    const float* __restrict__ w_proj, const float* __restrict__ b_proj,
    float* __restrict__ out, float* __restrict__ state,
    int t0, int t1)
{
    const int tid  = threadIdx.x;
    const int w    = tid >> 6;     // wave 0..7
    const int lane = tid & 63;
    const int ln   = lane & 15;
    const int kq   = lane >> 4;
    const int wh   = w & 3;
    const int f    = w >> 2;
    const int cg   = 16 * wh + ln + 64 * f;
    const int nT   = t1 - t0;      // multiple of 4

    __shared__ _Float16 h2_sh[2][HID_];
    __shared__ float pooled[HID_];

    // B-frags pre-scaled: r,z by log2(e); n by 2*log2(e) (exp2-direct gates)
    f16x8 wf[3][4];
    #pragma unroll
    for (int g = 0; g < 3; g++) {
        const float s = (g == 2) ? L2E2 : L2E;
        const float* wr = w_hh + (size_t)(128 * g + cg) * HID_;
        #pragma unroll
        for (int kc = 0; kc < 4; kc++) {
            const float* p = wr + kc * 32 + kq * 8;
            float4 q0 = *reinterpret_cast<const float4*>(p);
            float4 q1 = *reinterpret_cast<const float4*>(p + 4);
            q0.x *= s; q0.y *= s; q0.z *= s; q0.w *= s;
            q1.x *= s; q1.y *= s; q1.z *= s; q1.w *= s;
            wf[g][kc] = pack8_(q0, q1);
        }
    }
    const float bh = L2E2 * b_hh[256 + cg];

    float hj, hs;
    if (t0 == 0) { hj = hs = 0.f; }
    else {
        hj = state[b * HID_ + cg];
        hs = state[B_ * HID_ + b * HID_ + cg];
    }
    if (kq == 0) h2_sh[0][cg] = (_Float16)hj;
    __syncthreads();

    const float* gib = gi + (size_t)b * G3_;
    const size_t S = (size_t)B_ * G3_;

    float g0[3], g1[3], g2[3], g3[3];
    {
        const float* p0 = gib;
        const float* p1 = gib + S;
        g0[0] = p0[cg]; g0[1] = p0[cg + 128]; g0[2] = p0[cg + 256];
        g1[0] = p1[cg]; g1[1] = p1[cg + 128]; g1[2] = p1[cg + 256];
    }

    int pb = 0;
    const int nTm1 = nT - 1;
    for (int t = 0; t < nT; t += 4) {
        int t2 = t + 2 < nTm1 ? t + 2 : nTm1;
        int t3 = t + 3 < nTm1 ? t + 3 : nTm1;
        int t4 = t + 4 < nTm1 ? t + 4 : nTm1;
        int t5 = t + 5 < nTm1 ? t + 5 : nTm1;
        REC_STEP(g0, g2, t2, pb); pb ^= 1;
        REC_STEP(g1, g3, t3, pb); pb ^= 1;
        REC_STEP(g2, g0, t4, pb); pb ^= 1;
        REC_STEP(g3, g1, t5, pb); pb ^= 1;
    }

    if (t1 < T_) {
        if (kq == 0) {
            state[b * HID_ + cg]             = hj;
            state[B_ * HID_ + b * HID_ + cg] = hs;
        }
    } else {
        if (kq == 0) pooled[cg] = hs * (1.f / (float)T_);
        __syncthreads();
        if (tid < E_) {
            const float4* wpj = reinterpret_cast<const float4*>(w_proj + (size_t)tid * HID_);
            const float4* pp  = reinterpret_cast<const float4*>(pooled);
            float a0 = 0.f, a1 = 0.f, a2 = 0.f, a3 = 0.f;
            #pragma unroll
            for (int k = 0; k < 32; k++) {
                float4 wv = wpj[k]; float4 pv = pp[k];
                a0 = fmaf(wv.x, pv.x, a0);
                a1 = fmaf(wv.y, pv.y, a1);
                a2 = fmaf(wv.z, pv.z, a2);
                a3 = fmaf(wv.w, pv.w, a3);
            }
            out[b * E_ + tid] = (a0 + a1) + (a2 + a3) + b_proj[tid];
        }
    }
}

// ---------------------------------------------------------------------------
// Fused pipeline dispatch: blocks [0, nRec) run rec(chunk i-1), blocks
// [nRec, ...) run one gi_gemm job each for chunk i. rec reads the gi buffer
// written by the PREVIOUS dispatch (stream order = happens-before).
// r12 change: LDS pad 80 KB -> 56 KB = EXACTLY 2 blocks/CU.
//   - r9/r10 (no pad, 4 blocks/CU): gemm blocks pile onto rec CUs -> rec
//     co-run steps 1078 vs 781 cyc (38% tax).
//   - r11 (80 KB, 1 block/CU): rec protected (tail 776 cyc/step) but gemm
//     starved of residency -> co-run stages went gemm-bound (+170us).
//   - 56 KB: rec shares with AT MOST ONE gemm block (24+12 MFMA/step on the
//     CU instead of 24+36), gemm keeps 2-block latency hiding.
// ---------------------------------------------------------------------------
__global__ __launch_bounds__(512, 1)
void fused(const float* __restrict__ x, const float* __restrict__ w_ih,
           const float* __restrict__ b_ih, const float* __restrict__ w_hh,
           const float* __restrict__ b_hh,
           const float* __restrict__ w_proj, const float* __restrict__ b_proj,
           const float* __restrict__ gi_rec, float* __restrict__ gi_out,
           float* __restrict__ out, float* __restrict__ state,
           int trec0, int trec1, int tg0, int nRec, int nTiles)
{
    extern __shared__ char lds_pad_[];   // sized via launch config (pad only)
    (void)lds_pad_;
    const int bid = (int)blockIdx.x;
    if (bid < nRec) {
        rec_body(bid, gi_rec, w_hh, b_hh, w_proj, b_proj, out, state, trec0, trec1);
    } else {
        gemm_body(bid - nRec, nTiles, tg0, x, w_ih, b_ih, b_hh, gi_out);
    }
}

extern "C" void kernel_launch(void* const* d_in, const int* in_sizes, int n_in,
                              void* d_out, int out_size, void* d_ws, size_t ws_size,
                              hipStream_t stream)
{
    const float* x      = (const float*)d_in[0];
    const float* w_ih   = (const float*)d_in[1];
    const float* w_hh   = (const float*)d_in[2];
    const float* b_ih   = (const float*)d_in[3];
    const float* b_hh   = (const float*)d_in[4];
    const float* w_proj = (const float*)d_in[5];
    const float* b_proj = (const float*)d_in[6];
    float* out = (float*)d_out;

    const size_t state_bytes = (size_t)2 * B_ * HID_ * sizeof(float);
    const size_t per_t = (size_t)B_ * G3_ * sizeof(float);
    const unsigned LDS_PAD = 56 * 1024;   // 2 blocks/CU (160/57 = 2)

    // Schedule {128, 384, 1536} (r11): minimal exposed prologue, 512 co-run
    // steps, 1536-step contention-free tail (measured 776 cyc/step @ r11).
    const int NCK = 3;
    const int ck[NCK] = {128, 384, 1536};
    const size_t buf0_rows = 1536, buf1_rows = 384;   // c0,c2 -> buf0; c1 -> buf1
    const size_t need = (buf0_rows + buf1_rows) * per_t + state_bytes;

    if (ws_size >= need) {
        float* buf[2] = { (float*)d_ws,
                          (float*)((char*)d_ws + buf0_rows * per_t) };
        float* state  = (float*)((char*)d_ws + (buf0_rows + buf1_rows) * per_t);
        int st[NCK + 1];
        st[0] = 0;
        for (int i = 0; i < NCK; i++) st[i + 1] = st[i] + ck[i];
        for (int i = 0; i <= NCK; i++) {
            const int rb    = (i > 0)   ? B_ : 0;
            const int gb    = (i < NCK) ? (ck[i] / TS_) * B_ : 0;
            const int trec0 = (i > 0) ? st[i - 1] : 0;
            const int trec1 = (i > 0) ? st[i]     : 0;
            const int tg0   = (i < NCK) ? st[i] : 0;
            const int nT    = (i < NCK) ? ck[i] / TS_ : 1;
            fused<<<dim3(rb + gb), dim3(512), LDS_PAD, stream>>>(
                x, w_ih, b_ih, w_hh, b_hh, w_proj, b_proj,
                buf[(i + 1) & 1] /* = buf[(i-1)&1] */, buf[i & 1],
                out, state, trec0, trec1, tg0, rb, nT);
        }
    } else {
        // Serial fallback: single buffer, gemm dispatch then rec dispatch
        // (no LDS pad -- dense gemm grids want multi-block residency).
        size_t avail = ws_size > state_bytes ? ws_size - state_bytes : 0;
        int cT = (int)(avail / per_t);
        if (cT > T_) cT = T_;
        cT &= ~(TS_ - 1);
        if (cT < TS_) cT = TS_;
        float* buf0  = (float*)d_ws;
        float* state = (float*)((char*)d_ws + (size_t)cT * per_t);
        for (int t0 = 0; t0 < T_; t0 += cT) {
            int t1 = t0 + cT; if (t1 > T_) t1 = T_;
            int nt = t1 - t0;
            fused<<<dim3((nt / TS_) * B_), dim3(512), 0, stream>>>(
                x, w_ih, b_ih, w_hh, b_hh, w_proj, b_proj,
                buf0, buf0, out, state, 0, 0, t0, 0, nt / TS_);
            fused<<<dim3(B_), dim3(512), 0, stream>>>(
                x, w_ih, b_ih, w_hh, b_hh, w_proj, b_proj,
                buf0, buf0, out, state, t0, t1, 0, B_, nt / TS_);
        }
    }
}

// Round 13
// 833.702 us; speedup vs baseline: 1.0669x; 1.0478x over previous
//
#include <hip/hip_runtime.h>
#include <math.h>

#define B_   64
#define T_   2048
#define HID_ 128
#define G3_  384   // 3*HID
#define IN_  128
#define E_   64

#define TS_  128   // t-tile of gi GEMM block
#define CT_  512   // pipeline chunk (r8-verified structure)

typedef _Float16 f16x8 __attribute__((ext_vector_type(8)));
typedef float    f32x4 __attribute__((ext_vector_type(4)));

#define L2E  1.4426950408889634f   // log2(e)
#define L2E2 2.8853900817779268f   // 2*log2(e)

#if __has_builtin(__builtin_amdgcn_exp2f)
#define EXP2(x) __builtin_amdgcn_exp2f(x)
#else
#define EXP2(x) __expf((x) * 0.6931471805599453f)
#endif

__device__ __forceinline__ float rcp_(float x) { return __builtin_amdgcn_rcpf(x); }

// pack 8 f32 -> f16x8 via 4x cvt_pkrtz
__device__ __forceinline__ f16x8 pack8_(float4 a, float4 b) {
    uint4 u;
    u.x = __builtin_bit_cast(unsigned, __builtin_amdgcn_cvt_pkrtz(a.x, a.y));
    u.y = __builtin_bit_cast(unsigned, __builtin_amdgcn_cvt_pkrtz(a.z, a.w));
    u.z = __builtin_bit_cast(unsigned, __builtin_amdgcn_cvt_pkrtz(b.x, b.y));
    u.w = __builtin_bit_cast(unsigned, __builtin_amdgcn_cvt_pkrtz(b.z, b.w));
    return __builtin_bit_cast(f16x8, u);
}

// ---------------------------------------------------------------------------
// gi GEMM body (r8-passing version, unchanged). 8 waves / 512 threads, two
// column passes of 12 n-tiles. MFMA layout session-verified.
// ---------------------------------------------------------------------------
__device__ __forceinline__ void gemm_body(
    int g, int nTiles, int t0,
    const float* __restrict__ x, const float* __restrict__ w_ih,
    const float* __restrict__ b_ih, const float* __restrict__ b_hh,
    float* __restrict__ gi)
{
    const int tid = threadIdx.x;
    const int w   = tid >> 6;      // 0..7
    const int l   = tid & 63;
    const int ln  = l & 15;
    const int kq  = l >> 4;
    const int tt  = g % nTiles;
    const int b   = g / nTiles;
    const int tl_base = tt * TS_ + w * 16;

    const float* xb = x + ((size_t)b * T_ + (size_t)(t0 + tl_base)) * IN_;

    f16x8 afr[4];
    #pragma unroll
    for (int kc = 0; kc < 4; kc++) {
        const float* xr = xb + (size_t)ln * IN_ + kc * 32 + kq * 8;
        float4 p0 = *reinterpret_cast<const float4*>(xr);
        float4 p1 = *reinterpret_cast<const float4*>(xr + 4);
        afr[kc] = pack8_(p0, p1);
    }

    #pragma unroll
    for (int half = 0; half < 2; half++) {
        f32x4 acc[12];
        #pragma unroll
        for (int j = 0; j < 12; j++) acc[j] = (f32x4){0.f, 0.f, 0.f, 0.f};

        #pragma unroll
        for (int kc = 0; kc < 4; kc++) {
            #pragma unroll
            for (int j = 0; j < 12; j++) {
                const int nt = half * 12 + j;
                const float* wr = w_ih + (size_t)(nt * 16 + ln) * IN_ + kc * 32 + kq * 8;
                float4 q0 = *reinterpret_cast<const float4*>(wr);
                float4 q1 = *reinterpret_cast<const float4*>(wr + 4);
                const f16x8 bfr = pack8_(q0, q1);
                acc[j] = __builtin_amdgcn_mfma_f32_16x16x32_f16(afr[kc], bfr, acc[j], 0, 0, 0);
            }
        }

        #pragma unroll
        for (int j = 0; j < 12; j++) {
            const int col = half * 192 + j * 16 + ln;
            const float bias = b_ih[col] + (col < 256 ? b_hh[col] : 0.f);
            #pragma unroll
            for (int r = 0; r < 4; r++) {
                const size_t trow = (size_t)(tl_base + kq * 4 + r);   // chunk-relative
                gi[trow * (B_ * G3_) + (size_t)b * G3_ + col] = acc[j][r] + bias;
            }
        }
    }
}

// ---------------------------------------------------------------------------
// GRU recurrence core step (r9-verified gate math and issue order, gi loads
// REMOVED from the step). Consumes CUR = this step's gi (already in regs).
// The __syncthreads drain finds vmcnt==0 on 7 of 8 steps -> free.
// ---------------------------------------------------------------------------
#define REC_CORE(CUR)                                                          \
  {                                                                            \
    const char* hb_ = (const char*)(&h2_sh[pb][0]) + kq * 16;                  \
    f16x8 af_[4];                                                              \
    af_[0] = __builtin_bit_cast(f16x8, *(const uint4*)(hb_));                  \
    af_[1] = __builtin_bit_cast(f16x8, *(const uint4*)(hb_ + 64));             \
    af_[2] = __builtin_bit_cast(f16x8, *(const uint4*)(hb_ + 128));            \
    af_[3] = __builtin_bit_cast(f16x8, *(const uint4*)(hb_ + 192));            \
    f32x4 a0_ = (f32x4){0.f, 0.f, 0.f, 0.f};                                   \
    f32x4 a1_ = (f32x4){0.f, 0.f, 0.f, 0.f};                                   \
    f32x4 a2_ = (f32x4){0.f, 0.f, 0.f, 0.f};                                   \
    a0_ = __builtin_amdgcn_mfma_f32_16x16x32_f16(af_[0], wf[0][0], a0_, 0, 0, 0); \
    a0_ = __builtin_amdgcn_mfma_f32_16x16x32_f16(af_[1], wf[0][1], a0_, 0, 0, 0); \
    a0_ = __builtin_amdgcn_mfma_f32_16x16x32_f16(af_[2], wf[0][2], a0_, 0, 0, 0); \
    a0_ = __builtin_amdgcn_mfma_f32_16x16x32_f16(af_[3], wf[0][3], a0_, 0, 0, 0); \
    a2_ = __builtin_amdgcn_mfma_f32_16x16x32_f16(af_[0], wf[2][0], a2_, 0, 0, 0); \
    a2_ = __builtin_amdgcn_mfma_f32_16x16x32_f16(af_[1], wf[2][1], a2_, 0, 0, 0); \
    a2_ = __builtin_amdgcn_mfma_f32_16x16x32_f16(af_[2], wf[2][2], a2_, 0, 0, 0); \
    a2_ = __builtin_amdgcn_mfma_f32_16x16x32_f16(af_[3], wf[2][3], a2_, 0, 0, 0); \
    const float yr_ = fmaf(CUR[0], L2E, a0_[0]);                               \
    const float r_  = rcp_(1.f + EXP2(-yr_));                                  \
    a1_ = __builtin_amdgcn_mfma_f32_16x16x32_f16(af_[0], wf[1][0], a1_, 0, 0, 0); \
    a1_ = __builtin_amdgcn_mfma_f32_16x16x32_f16(af_[1], wf[1][1], a1_, 0, 0, 0); \
    a1_ = __builtin_amdgcn_mfma_f32_16x16x32_f16(af_[2], wf[1][2], a1_, 0, 0, 0); \
    a1_ = __builtin_amdgcn_mfma_f32_16x16x32_f16(af_[3], wf[1][3], a1_, 0, 0, 0); \
    const float q_  = CUR[2] * L2E2;                                           \
    const float yn_ = fmaf(r_, a2_[0] + bh, q_);                               \
    const float u_  = rcp_(1.f + EXP2(yn_));                                   \
    const float n_  = fmaf(-2.f, u_, 1.f);                                     \
    const float yz_ = fmaf(CUR[1], L2E, a1_[0]);                               \
    const float z_  = rcp_(1.f + EXP2(-yz_));                                  \
    hj = n_ + z_ * (hj - n_);                                                  \
    hs += hj;                                                                  \
    if (kq == 0) h2_sh[pb ^ 1][cg] = (_Float16)hj;                             \
    __syncthreads();                                                           \
    pb ^= 1;                                                                   \
  }

// burst-load 8 steps' gi (rows TB..TB+7, clamped) into a register array.
// 24 loads issued together; their latency is absorbed by ONE barrier drain
// instead of 8 (the r13 change). Clamped rows are never consumed (nT%16==0).
#define LOAD8(DST, TB)                                                         \
  _Pragma("unroll")                                                            \
  for (int j = 0; j < 8; j++) {                                                \
    int rr_ = (TB) + j; rr_ = rr_ < nTm1 ? rr_ : nTm1;                         \
    const float* gp_ = gib + (size_t)rr_ * S;                                  \
    DST[j][0] = gp_[cg]; DST[j][1] = gp_[cg + 128]; DST[j][2] = gp_[cg + 256]; \
  }

#define STEP8(SRC)                                                             \
  _Pragma("unroll")                                                            \
  for (int j = 0; j < 8; j++) { REC_CORE(SRC[j]); }

// ---------------------------------------------------------------------------
// GRU recurrence body. 8 waves (2/SIMD). r13: gi is block-burst prefetched
// into registers 8 steps at a time, double-buffered (gA/gB, all indices
// compile-time so the arrays live in VGPRs). Per 8 steps: one LOAD8 burst
// (24 loads) -> one expensive drain + 7 free ones, vs 8 exposed drains
// before. Also shrinks co-run tax (gemm's gi-write churn raised rec's gi
// latency; amortization caps its cost at ~1/8).
// ---------------------------------------------------------------------------
__device__ __forceinline__ void rec_body(
    int b,
    const float* __restrict__ gi, const float* __restrict__ w_hh,
    const float* __restrict__ b_hh,
    const float* __restrict__ w_proj, const float* __restrict__ b_proj,
    float* __restrict__ out, float* __restrict__ state,
    int t0, int t1)
{
    const int tid  = threadIdx.x;
    const int w    = tid >> 6;     // wave 0..7
    const int lane = tid & 63;
    const int ln   = lane & 15;
    const int kq   = lane >> 4;
    const int wh   = w & 3;
    const int f    = w >> 2;
    const int cg   = 16 * wh + ln + 64 * f;
    const int nT   = t1 - t0;      // multiple of 16 (chunks are multiples of 128)

    __shared__ _Float16 h2_sh[2][HID_];
    __shared__ float pooled[HID_];

    // B-frags pre-scaled: r,z by log2(e); n by 2*log2(e) (exp2-direct gates)
    f16x8 wf[3][4];
    #pragma unroll
    for (int g = 0; g < 3; g++) {
        const float s = (g == 2) ? L2E2 : L2E;
        const float* wr = w_hh + (size_t)(128 * g + cg) * HID_;
        #pragma unroll
        for (int kc = 0; kc < 4; kc++) {
            const float* p = wr + kc * 32 + kq * 8;
            float4 q0 = *reinterpret_cast<const float4*>(p);
            float4 q1 = *reinterpret_cast<const float4*>(p + 4);
            q0.x *= s; q0.y *= s; q0.z *= s; q0.w *= s;
            q1.x *= s; q1.y *= s; q1.z *= s; q1.w *= s;
            wf[g][kc] = pack8_(q0, q1);
        }
    }
    const float bh = L2E2 * b_hh[256 + cg];

    float hj, hs;
    if (t0 == 0) { hj = hs = 0.f; }
    else {
        hj = state[b * HID_ + cg];
        hs = state[B_ * HID_ + b * HID_ + cg];
    }

    const float* gib = gi + (size_t)b * G3_;
    const size_t S = (size_t)B_ * G3_;
    const int nTm1 = nT - 1;

    // preload first 8 steps' gi; its latency drains at the init barrier
    float gA[8][3], gB[8][3];
    LOAD8(gA, 0);

    if (kq == 0) h2_sh[0][cg] = (_Float16)hj;
    __syncthreads();

    int pb = 0;
    for (int tb = 0; tb < nT; tb += 16) {
        LOAD8(gB, tb + 8);    // burst for steps tb+8..tb+15
        STEP8(gA);            // steps tb..tb+7
        LOAD8(gA, tb + 16);   // burst for steps tb+16..tb+23 (next iter)
        STEP8(gB);            // steps tb+8..tb+15
    }

    if (t1 < T_) {
        if (kq == 0) {
            state[b * HID_ + cg]             = hj;
            state[B_ * HID_ + b * HID_ + cg] = hs;
        }
    } else {
        if (kq == 0) pooled[cg] = hs * (1.f / (float)T_);
        __syncthreads();
        if (tid < E_) {
            const float4* wpj = reinterpret_cast<const float4*>(w_proj + (size_t)tid * HID_);
            const float4* pp  = reinterpret_cast<const float4*>(pooled);
            float a0 = 0.f, a1 = 0.f, a2 = 0.f, a3 = 0.f;
            #pragma unroll
            for (int k = 0; k < 32; k++) {
                float4 wv = wpj[k]; float4 pv = pp[k];
                a0 = fmaf(wv.x, pv.x, a0);
                a1 = fmaf(wv.y, pv.y, a1);
                a2 = fmaf(wv.z, pv.z, a2);
                a3 = fmaf(wv.w, pv.w, a3);
            }
            out[b * E_ + tid] = (a0 + a1) + (a2 + a3) + b_proj[tid];
        }
    }
}

// ---------------------------------------------------------------------------
// Fused pipeline dispatch (r8-passing structure, byte-identical wrapper):
// blocks [0, nRec) run rec(chunk i-1), blocks [nRec, ...) run gi_gemm
// (chunk i). rec reads the gi buffer written by the PREVIOUS dispatch
// (stream order = happens-before). rec blocks first in the grid.
// ---------------------------------------------------------------------------
__global__ __launch_bounds__(512, 1)
void fused(const float* __restrict__ x, const float* __restrict__ w_ih,
           const float* __restrict__ b_ih, const float* __restrict__ w_hh,
           const float* __restrict__ b_hh,
           const float* __restrict__ w_proj, const float* __restrict__ b_proj,
           const float* __restrict__ gi_rec, float* __restrict__ gi_out,
           float* __restrict__ out, float* __restrict__ state,
           int trec0, int trec1, int tg0, int nRec, int nTiles)
{
    const int bid = (int)blockIdx.x;
    if (bid < nRec) {
        rec_body(bid, gi_rec, w_hh, b_hh, w_proj, b_proj, out, state, trec0, trec1);
    } else {
        gemm_body(bid - nRec, nTiles, tg0, x, w_ih, b_ih, b_hh, gi_out);
    }
}

extern "C" void kernel_launch(void* const* d_in, const int* in_sizes, int n_in,
                              void* d_out, int out_size, void* d_ws, size_t ws_size,
                              hipStream_t stream)
{
    const float* x      = (const float*)d_in[0];
    const float* w_ih   = (const float*)d_in[1];
    const float* w_hh   = (const float*)d_in[2];
    const float* b_ih   = (const float*)d_in[3];
    const float* b_hh   = (const float*)d_in[4];
    const float* w_proj = (const float*)d_in[5];
    const float* b_proj = (const float*)d_in[6];
    float* out = (float*)d_out;

    const size_t state_bytes = (size_t)2 * B_ * HID_ * sizeof(float);
    const size_t per_t = (size_t)B_ * G3_ * sizeof(float);

    if (ws_size >= 2 * (size_t)CT_ * per_t + state_bytes) {
        // Pipelined path: double-buffered CT_-sized gi chunks (r8 schedule).
        float* buf[2] = { (float*)d_ws,
                          (float*)((char*)d_ws + (size_t)CT_ * per_t) };
        float* state  = (float*)((char*)d_ws + 2 * (size_t)CT_ * per_t);
        const int nTiles = CT_ / TS_;        // 4
        const int nC = T_ / CT_;             // 4
        for (int i = 0; i <= nC; i++) {
            const int rb = (i > 0)  ? B_ : 0;
            const int gb = (i < nC) ? nTiles * B_ : 0;
            fused<<<dim3(rb + gb), dim3(512), 0, stream>>>(
                x, w_ih, b_ih, w_hh, b_hh, w_proj, b_proj,
                buf[(i + 1) & 1] /* = buf[(i-1)&1] */, buf[i & 1],
                out, state,
                (i - 1) * CT_, i * CT_, i * CT_, rb, nTiles);
        }
    } else {
        // Serial fallback: single buffer, gemm dispatch then rec dispatch.
        size_t avail = ws_size > state_bytes ? ws_size - state_bytes : 0;
        int cT = (int)(avail / per_t);
        if (cT > T_) cT = T_;
        cT &= ~(TS_ - 1);
        if (cT < TS_) cT = TS_;
        float* buf0  = (float*)d_ws;
        float* state = (float*)((char*)d_ws + (size_t)cT * per_t);
        for (int t0 = 0; t0 < T_; t0 += cT) {
            int t1 = t0 + cT; if (t1 > T_) t1 = T_;
            int nt = t1 - t0;
            fused<<<dim3((nt / TS_) * B_), dim3(512), 0, stream>>>(
                x, w_ih, b_ih, w_hh, b_hh, w_proj, b_proj,
                buf0, buf0, out, state, 0, 0, t0, 0, nt / TS_);
            fused<<<dim3(B_), dim3(512), 0, stream>>>(
                x, w_ih, b_ih, w_hh, b_hh, w_proj, b_proj,
                buf0, buf0, out, state, t0, t1, 0, B_, nt / TS_);
        }
    }
}